// Round 4
// baseline (1482.685 us; speedup 1.0000x reference)
//
#include <hip/hip_runtime.h>
#include <hip/hip_bf16.h>

#define NN 100000
#define NE 600000
#define DD 128
#define NL 3
#define NG 64
#define LN_EPS 1e-5f

typedef __attribute__((ext_vector_type(8))) short short8v;
typedef __attribute__((ext_vector_type(8))) unsigned short ushort8v;
typedef __attribute__((ext_vector_type(4))) float f32x4;
typedef __attribute__((ext_vector_type(4))) unsigned int uint4v;
typedef unsigned short ushort;
typedef unsigned int uint;

// unpack dword of 2 bf16 (cols 2m, 2m+1) to fp32
__device__ inline float2 unpk2(uint u) {
  float2 r;
  r.x = __uint_as_float(u << 16);
  r.y = __uint_as_float(u & 0xffff0000u);
  return r;
}

// split fp32 pair -> (hi bf16 pair, lo bf16 pair); hi = truncate, lo = RNE(residual)
__device__ inline void split2(float ax, float ay, uint& hi2, uint& lo2) {
  const uint ux = __float_as_uint(ax), uy = __float_as_uint(ay);
  hi2 = (ux >> 16) | (uy & 0xffff0000u);
  const float rx = ax - __uint_as_float(ux & 0xffff0000u);
  const float ry = ay - __uint_as_float(uy & 0xffff0000u);
  __hip_bfloat16 bx = __float2bfloat16(rx), by = __float2bfloat16(ry);
  lo2 = (uint)*(ushort*)&bx | ((uint)*(ushort*)&by << 16);
}

// ============ CSR build ============
__global__ __launch_bounds__(256)
void count_kernel(const int* __restrict__ dst, int* __restrict__ deg) {
  const int e = blockIdx.x * 256 + threadIdx.x;
  if (e < NE) atomicAdd(&deg[dst[e]], 1);
}

__global__ __launch_bounds__(256)
void scan_a(const int* __restrict__ deg, int* __restrict__ off, int* __restrict__ btot) {
  __shared__ int wsum[4];
  const int t = threadIdx.x, lane = t & 63, wid = t >> 6;
  const int base = blockIdx.x * 1024 + t * 4;
  int4 d = {0, 0, 0, 0};
  if (base < NN) d = *(const int4*)(deg + base);
  const int s0 = d.x, s1 = s0 + d.y, s2 = s1 + d.z, s3 = s2 + d.w;
  int v = s3;
#pragma unroll
  for (int o = 1; o < 64; o <<= 1) { const int u = __shfl_up(v, o); if (lane >= o) v += u; }
  if (lane == 63) wsum[wid] = v;
  __syncthreads();
  if (t == 0) {
    int a = 0;
#pragma unroll
    for (int i = 0; i < 4; ++i) { const int x = wsum[i]; wsum[i] = a; a += x; }
    btot[blockIdx.x] = a;
  }
  __syncthreads();
  const int texcl = wsum[wid] + v - s3;
  if (base < NN) {
    const int4 o4 = {texcl, texcl + s0, texcl + s1, texcl + s2};
    *(int4*)(off + base) = o4;
  }
}

__global__ __launch_bounds__(128)
void scan_b(int* __restrict__ btot, int nb) {
  __shared__ int wsum[2];
  const int t = threadIdx.x, lane = t & 63, wid = t >> 6;
  const int x = (t < nb) ? btot[t] : 0;
  int v = x;
#pragma unroll
  for (int o = 1; o < 64; o <<= 1) { const int u = __shfl_up(v, o); if (lane >= o) v += u; }
  if (lane == 63) wsum[wid] = v;
  __syncthreads();
  if (t == 0) { const int w0 = wsum[0]; wsum[0] = 0; wsum[1] = w0; }
  __syncthreads();
  const int excl = wsum[wid] + v - x;
  if (t < nb) btot[t] = excl;
}

__global__ __launch_bounds__(256)
void scan_c(int* __restrict__ off, const int* __restrict__ btot) {
  const int i = blockIdx.x * 256 + threadIdx.x;
  if (i < NN) off[i] += btot[i >> 10];
}

// fill: atomicAdd turns off[] starts into ends; csr = src, edst = dst per slot
__global__ __launch_bounds__(256)
void fill_kernel(const int* __restrict__ src, const int* __restrict__ dst,
                 int* __restrict__ off, int* __restrict__ csr, int* __restrict__ edst) {
  const int e = blockIdx.x * 256 + threadIdx.x;
  if (e < NE) {
    const int d = dst[e];
    const int p = atomicAdd(&off[d], 1);
    csr[p] = src[e];
    edst[p] = d;
  }
}

// ============ weight prep: fragment-ordered bf16 hi/lo ============
__global__ __launch_bounds__(256)
void wprep_kernel(const float* __restrict__ projW, const float* __restrict__ mlpW,
                  ushort* __restrict__ Wp) {
  const int tid = blockIdx.x * 256 + threadIdx.x;   // 8192 total
  const int lane = tid & 63;
  const int fid = tid >> 6;                         // 0..127
  const int mat = fid >> 5;
  const int rem = fid & 31;
  const int kk = rem >> 3, nf = rem & 7;
  const float* W = (mat == 0) ? projW : (mlpW + (size_t)(mat - 1) * DD * DD);
  const int k0 = kk * 32 + (lane >> 4) * 8;
  const int col = nf * 16 + (lane & 15);
  ushort8v hv, lv;
#pragma unroll
  for (int j = 0; j < 8; ++j) {
    const float f = W[(size_t)(k0 + j) * DD + col];
    __hip_bfloat16 bh = __float2bfloat16(f);
    __hip_bfloat16 bl = __float2bfloat16(f - __bfloat162float(bh));
    hv[j] = *(ushort*)&bh;
    lv[j] = *(ushort*)&bl;
  }
  ushort* base = Wp + (size_t)mat * 32768;
  *(ushort8v*)(base + ((size_t)((kk * 8 + nf) * 2 + 0) * 64 + lane) * 8) = hv;
  *(ushort8v*)(base + ((size_t)((kk * 8 + nf) * 2 + 1) * 64 + lane) * 8) = lv;
}

// ============ fused [edge-streamed gather +] GEMM + ReLU [+ LN] ============
// LDS: acc[64][128] fp32 (32 KB). Position layout within a row:
//   col c -> pos (c&1)*64 + (c>>1); byte addr swizzled per 16B chunk:
//   pos' = ((pos>>2) ^ (row&7))*4 + (pos&3).
// Phase 1: init acc with self term (MODE1: bf16 h row; MODE0: fp32 X row).
// Phase 2 (MODE1): stream block's CSR edge range, 8 edges/iter/wave,
//   2 conflict-free ds_add_f32 per lane per edge (pos lane, 64+lane).
// Phase 3: each lane reads its A-frag from acc (2 x b128 per kk), splits
//   hi/lo bf16 in registers, 96 MFMAs, fused bias+ReLU[+LN], bf16 store.
template<int MODE>
__global__ __launch_bounds__(256)
void gemm_node(const float* __restrict__ Xf, const ushort* __restrict__ Hin,
               const int* __restrict__ csr, const int* __restrict__ edst,
               const int* __restrict__ offE,
               const ushort* __restrict__ Wp, const float* __restrict__ bias,
               const float* __restrict__ lng, const float* __restrict__ lnb,
               ushort* __restrict__ Hout) {
  __shared__ float acc[64 * 128];
  const int t = threadIdx.x, lane = t & 63, w = t >> 6;
  const int r0 = blockIdx.x * 64;

  { // ---- phase 1: init (4 threads per row, 32 cols each) ----
    const int row = t >> 2;
    const int v = r0 + row;
    const int cq = (t & 3) * 32;
    float ev[16], od[16];
    if (v < NN) {
      if constexpr (MODE == 0) {
        const float* xp = Xf + (size_t)v * DD + cq;
#pragma unroll
        for (int m = 0; m < 16; ++m) { ev[m] = xp[2 * m]; od[m] = xp[2 * m + 1]; }
      } else {
        const uint* hp = (const uint*)Hin + (size_t)v * 64 + (cq >> 1);
#pragma unroll
        for (int m = 0; m < 16; ++m) { const float2 f = unpk2(hp[m]); ev[m] = f.x; od[m] = f.y; }
      }
    } else {
#pragma unroll
      for (int m = 0; m < 16; ++m) { ev[m] = 0.f; od[m] = 0.f; }
    }
    const int pbase = cq >> 1;           // chunk-aligned even-region base
#pragma unroll
    for (int j = 0; j < 4; ++j) {
      const int pos = pbase + 4 * j;
      const int chs = (((pos >> 2) ^ (row & 7)) << 2);
      const float4 ve = {ev[4 * j], ev[4 * j + 1], ev[4 * j + 2], ev[4 * j + 3]};
      const float4 vo = {od[4 * j], od[4 * j + 1], od[4 * j + 2], od[4 * j + 3]};
      *(float4*)&acc[row * 128 + chs] = ve;
      *(float4*)&acc[row * 128 + 64 + chs] = vo;
    }
  }
  __syncthreads();

  if constexpr (MODE == 1) { // ---- phase 2: edge stream ----
    const uint* hu = (const uint*)Hin;
    const int e0 = (r0 == 0) ? 0 : offE[r0 - 1];
    const int rlast = (r0 + 63 < NN) ? (r0 + 63) : (NN - 1);
    const int e1 = offE[rlast];
    const int len = e1 - e0;
    int i = e0 + ((len * w) >> 2);
    const int we_ = e0 + ((len * (w + 1)) >> 2);
    for (; i + 8 <= we_; i += 8) {
      int sv[8], dv[8];
      uint uv[8];
#pragma unroll
      for (int j = 0; j < 8; ++j) { sv[j] = csr[i + j]; dv[j] = edst[i + j] - r0; }
#pragma unroll
      for (int j = 0; j < 8; ++j) uv[j] = hu[(size_t)sv[j] * 64 + lane];
#pragma unroll
      for (int j = 0; j < 8; ++j) {
        const float2 f = unpk2(uv[j]);
        const int ce = ((((lane >> 2) ^ (dv[j] & 7)) << 2) | (lane & 3));
        float* rp = &acc[dv[j] * 128 + ce];
        atomicAdd(rp, f.x);
        atomicAdd(rp + 64, f.y);
      }
    }
    for (; i < we_; ++i) {
      const int d = edst[i] - r0;
      const float2 f = unpk2(hu[(size_t)csr[i] * 64 + lane]);
      const int ce = ((((lane >> 2) ^ (d & 7)) << 2) | (lane & 3));
      float* rp = &acc[d * 128 + ce];
      atomicAdd(rp, f.x);
      atomicAdd(rp + 64, f.y);
    }
  }
  __syncthreads();

  // ---- phase 3: frag read + MFMA ----
  f32x4 accv[8];
#pragma unroll
  for (int nf = 0; nf < 8; ++nf) accv[nf] = (f32x4){0.f, 0.f, 0.f, 0.f};
  const int arow = w * 16 + (lane & 15);
  const int q = lane >> 4;
  const int rx = arow & 7;
#pragma unroll
  for (int kk = 0; kk < 4; ++kk) {
    const int chs = (((kk * 4 + q) ^ rx) << 2);
    const float4 ve = *(const float4*)&acc[arow * 128 + chs];
    const float4 vo = *(const float4*)&acc[arow * 128 + 64 + chs];
    uint hh0, hh1, hh2, hh3, ll0, ll1, ll2, ll3;
    split2(ve.x, vo.x, hh0, ll0);
    split2(ve.y, vo.y, hh1, ll1);
    split2(ve.z, vo.z, hh2, ll2);
    split2(ve.w, vo.w, hh3, ll3);
    const uint4v h4 = {hh0, hh1, hh2, hh3};
    const uint4v l4 = {ll0, ll1, ll2, ll3};
    const short8v ah = __builtin_bit_cast(short8v, h4);
    const short8v al = __builtin_bit_cast(short8v, l4);
#pragma unroll
    for (int nf = 0; nf < 8; ++nf) {
      const ushort* bp = Wp + ((size_t)((kk * 8 + nf) * 2) * 64 + lane) * 8;
      const short8v bh = *(const short8v*)bp;
      const short8v bl = *(const short8v*)(bp + 64 * 8);
      accv[nf] = __builtin_amdgcn_mfma_f32_16x16x32_bf16(ah, bh, accv[nf], 0, 0, 0);
      accv[nf] = __builtin_amdgcn_mfma_f32_16x16x32_bf16(al, bh, accv[nf], 0, 0, 0);
      accv[nf] = __builtin_amdgcn_mfma_f32_16x16x32_bf16(ah, bl, accv[nf], 0, 0, 0);
    }
  }

  // ---- epilogue: bias + ReLU [+ LN], store bf16 ----
  const int colb = lane & 15;
  float bias8[8], g8[8], q8[8];
#pragma unroll
  for (int nf = 0; nf < 8; ++nf) {
    bias8[nf] = bias[nf * 16 + colb];
    if (MODE == 1) { g8[nf] = lng[nf * 16 + colb]; q8[nf] = lnb[nf * 16 + colb]; }
  }
#pragma unroll
  for (int r = 0; r < 4; ++r) {
    const int grow = r0 + w * 16 + (lane >> 4) * 4 + r;
    float z[8];
    float s = 0.f, s2 = 0.f;
#pragma unroll
    for (int nf = 0; nf < 8; ++nf) {
      z[nf] = fmaxf(accv[nf][r] + bias8[nf], 0.f);
      s += z[nf];
      s2 += z[nf] * z[nf];
    }
    if (MODE == 1) {
#pragma unroll
      for (int o = 1; o < 16; o <<= 1) { s += __shfl_xor(s, o); s2 += __shfl_xor(s2, o); }
      const float mu = s * (1.f / DD);
      const float inv = rsqrtf(s2 * (1.f / DD) - mu * mu + LN_EPS);
#pragma unroll
      for (int nf = 0; nf < 8; ++nf) z[nf] = (z[nf] - mu) * inv * g8[nf] + q8[nf];
    }
    if (grow < NN) {
      ushort* yp = Hout + (size_t)grow * DD + colb;
#pragma unroll
      for (int nf = 0; nf < 8; ++nf) {
        __hip_bfloat16 b = __float2bfloat16(z[nf]);
        yp[nf * 16] = *(ushort*)&b;
      }
    }
  }
}

// ============ pool (bf16 h, batch_ids sorted) ============
__global__ __launch_bounds__(128)
void pool_kernel(const ushort* __restrict__ h, const int* __restrict__ batch,
                 float* __restrict__ sums, float* __restrict__ counts) {
  const int c = threadIdx.x;
  const int base = blockIdx.x * 64;
  const int end = (base + 64 < NN) ? base + 64 : NN;
  int cur = batch[base];
  float acc = 0.f, cnt = 0.f;
  for (int r = base; r < end; ++r) {
    const int g = batch[r];
    if (g != cur) {
      __hip_atomic_fetch_add(&sums[cur * DD + c], acc, __ATOMIC_RELAXED, __HIP_MEMORY_SCOPE_AGENT);
      if (c == 0)
        __hip_atomic_fetch_add(&counts[cur], cnt, __ATOMIC_RELAXED, __HIP_MEMORY_SCOPE_AGENT);
      acc = 0.f; cnt = 0.f; cur = g;
    }
    acc += __uint_as_float(((uint)h[(size_t)r * DD + c]) << 16);
    cnt += 1.f;
  }
  __hip_atomic_fetch_add(&sums[cur * DD + c], acc, __ATOMIC_RELAXED, __HIP_MEMORY_SCOPE_AGENT);
  if (c == 0)
    __hip_atomic_fetch_add(&counts[cur], cnt, __ATOMIC_RELAXED, __HIP_MEMORY_SCOPE_AGENT);
}

__global__ __launch_bounds__(256)
void finalize_kernel(const float* __restrict__ sums, const float* __restrict__ counts,
                     float* __restrict__ out) {
  const int i = blockIdx.x * 256 + threadIdx.x;
  if (i >= NG * DD) return;
  out[i] = sums[i] / fmaxf(counts[i >> 7], 1.f);
}

extern "C" void kernel_launch(void* const* d_in, const int* in_sizes, int n_in,
                              void* d_out, int out_size, void* d_ws, size_t ws_size,
                              hipStream_t stream) {
  const float* x     = (const float*)d_in[0];
  const int*   ei    = (const int*)d_in[1];
  const int*   batch = (const int*)d_in[2];
  const float* projW = (const float*)d_in[3];
  const float* projb = (const float*)d_in[4];
  const float* mlpW  = (const float*)d_in[5];
  const float* mlpb  = (const float*)d_in[6];
  const float* lng   = (const float*)d_in[7];
  const float* lnb   = (const float*)d_in[8];
  float* out = (float*)d_out;

  char* ws = (char*)d_ws;
  ushort* hA    = (ushort*)(ws + 0);           // 25,600,000 B
  ushort* hB    = (ushort*)(ws + 25600000);    // 25,600,000 B
  int*   csr    = (int*)   (ws + 51200000);    //  2,400,000 B
  int*   edst   = (int*)   (ws + 53600000);    //  2,400,000 B
  int*   deg    = (int*)   (ws + 56000000);    //    400,000 B
  int*   off    = (int*)   (ws + 56400000);    //    400,000 B
  int*   btot   = (int*)   (ws + 56800000);    //        512 B
  ushort* Wp    = (ushort*)(ws + 56800512);    //    262,144 B
  float* sums   = (float*) (ws + 57062656);    //     32,768 B
  float* counts = (float*) (ws + 57095424);    //        256 B

  const int* src = ei;
  const int* dst = ei + NE;

  // ---- CSR build ----
  hipMemsetAsync(deg, 0, NN * sizeof(int), stream);
  count_kernel<<<(NE + 255) / 256, 256, 0, stream>>>(dst, deg);
  scan_a<<<(NN + 1023) / 1024, 256, 0, stream>>>(deg, off, btot);
  scan_b<<<1, 128, 0, stream>>>(btot, (NN + 1023) / 1024);
  scan_c<<<(NN + 255) / 256, 256, 0, stream>>>(off, btot);
  fill_kernel<<<(NE + 255) / 256, 256, 0, stream>>>(src, dst, off, csr, edst);

  // ---- weight prep ----
  wprep_kernel<<<32, 256, 0, stream>>>(projW, mlpW, Wp);

  const int gemm_blocks = (NN + 63) / 64;   // 1563

  // h = relu(x @ projW + projb) -> bf16
  gemm_node<0><<<gemm_blocks, 256, 0, stream>>>(
      x, nullptr, nullptr, nullptr, nullptr, Wp, projb, nullptr, nullptr, hA);

  // 3 fused GIN layers, ping-pong hA/hB
  ushort* hin = hA;
  ushort* hout = hB;
  for (int l = 0; l < NL; ++l) {
    gemm_node<1><<<gemm_blocks, 256, 0, stream>>>(
        nullptr, hin, csr, edst, off, Wp + (size_t)(1 + l) * 32768,
        mlpb + (size_t)l * DD, lng + (size_t)l * DD, lnb + (size_t)l * DD, hout);
    ushort* tmp = hin; hin = hout; hout = tmp;
  }

  hipMemsetAsync(sums, 0, (size_t)(NG * DD + NG) * sizeof(float), stream);
  pool_kernel<<<(NN + 63) / 64, 128, 0, stream>>>(hin, batch, sums, counts);
  finalize_kernel<<<(NG * DD + 255) / 256, 256, 0, stream>>>(sums, counts, out);
}

// Round 5
// 286.053 us; speedup vs baseline: 5.1833x; 5.1833x over previous
//
#include <hip/hip_runtime.h>
#include <hip/hip_bf16.h>

#define NN 100000
#define NE 600000
#define DD 128
#define NL 3
#define NG 64
#define LN_EPS 1e-5f

typedef __attribute__((ext_vector_type(8))) short short8v;
typedef __attribute__((ext_vector_type(8))) unsigned short ushort8v;
typedef __attribute__((ext_vector_type(4))) float f32x4;
typedef unsigned short ushort;
typedef unsigned int uint;

// unpack dword of 2 bf16 (cols c, c+1) to fp32
__device__ inline float2 unpk2(uint u) {
  float2 r;
  r.x = __uint_as_float(u << 16);
  r.y = __uint_as_float(u & 0xffff0000u);
  return r;
}

// split fp32 pair -> (hi bf16 pair, lo bf16 pair); hi = truncate, lo = RNE(residual)
__device__ inline void split2(float ax, float ay, uint& hi2, uint& lo2) {
  const uint ux = __float_as_uint(ax), uy = __float_as_uint(ay);
  hi2 = (ux >> 16) | (uy & 0xffff0000u);
  const float rx = ax - __uint_as_float(ux & 0xffff0000u);
  const float ry = ay - __uint_as_float(uy & 0xffff0000u);
  __hip_bfloat16 bx = __float2bfloat16(rx), by = __float2bfloat16(ry);
  lo2 = (uint)*(ushort*)&bx | ((uint)*(ushort*)&by << 16);
}

// ============ CSR build ============
__global__ __launch_bounds__(256)
void count_kernel(const int* __restrict__ dst, int* __restrict__ deg) {
  const int e = blockIdx.x * 256 + threadIdx.x;
  if (e < NE) atomicAdd(&deg[dst[e]], 1);
}

__global__ __launch_bounds__(256)
void scan_a(const int* __restrict__ deg, int* __restrict__ off, int* __restrict__ btot) {
  __shared__ int wsum[4];
  const int t = threadIdx.x, lane = t & 63, wid = t >> 6;
  const int base = blockIdx.x * 1024 + t * 4;
  int4 d = {0, 0, 0, 0};
  if (base < NN) d = *(const int4*)(deg + base);
  const int s0 = d.x, s1 = s0 + d.y, s2 = s1 + d.z, s3 = s2 + d.w;
  int v = s3;
#pragma unroll
  for (int o = 1; o < 64; o <<= 1) { const int u = __shfl_up(v, o); if (lane >= o) v += u; }
  if (lane == 63) wsum[wid] = v;
  __syncthreads();
  if (t == 0) {
    int a = 0;
#pragma unroll
    for (int i = 0; i < 4; ++i) { const int x = wsum[i]; wsum[i] = a; a += x; }
    btot[blockIdx.x] = a;
  }
  __syncthreads();
  const int texcl = wsum[wid] + v - s3;
  if (base < NN) {
    const int4 o4 = {texcl, texcl + s0, texcl + s1, texcl + s2};
    *(int4*)(off + base) = o4;
  }
}

__global__ __launch_bounds__(128)
void scan_b(int* __restrict__ btot, int nb) {
  __shared__ int wsum[2];
  const int t = threadIdx.x, lane = t & 63, wid = t >> 6;
  const int x = (t < nb) ? btot[t] : 0;
  int v = x;
#pragma unroll
  for (int o = 1; o < 64; o <<= 1) { const int u = __shfl_up(v, o); if (lane >= o) v += u; }
  if (lane == 63) wsum[wid] = v;
  __syncthreads();
  if (t == 0) { const int w0 = wsum[0]; wsum[0] = 0; wsum[1] = w0; }
  __syncthreads();
  const int excl = wsum[wid] + v - x;
  if (t < nb) btot[t] = excl;
}

__global__ __launch_bounds__(256)
void scan_c(int* __restrict__ off, const int* __restrict__ btot) {
  const int i = blockIdx.x * 256 + threadIdx.x;
  if (i < NN) off[i] += btot[i >> 10];
}

// fill: atomicAdd turns off[] starts into ends; csr = src per dst bucket
__global__ __launch_bounds__(256)
void fill_kernel(const int* __restrict__ src, const int* __restrict__ dst,
                 int* __restrict__ off, int* __restrict__ csr) {
  const int e = blockIdx.x * 256 + threadIdx.x;
  if (e < NE) {
    const int p = atomicAdd(&off[dst[e]], 1);
    csr[p] = src[e];
  }
}

// ============ weight prep: fragment-ordered bf16 hi/lo ============
__global__ __launch_bounds__(256)
void wprep_kernel(const float* __restrict__ projW, const float* __restrict__ mlpW,
                  ushort* __restrict__ Wp) {
  const int tid = blockIdx.x * 256 + threadIdx.x;   // 8192 total
  const int lane = tid & 63;
  const int fid = tid >> 6;                         // 0..127
  const int mat = fid >> 5;
  const int rem = fid & 31;
  const int kk = rem >> 3, nf = rem & 7;
  const float* W = (mat == 0) ? projW : (mlpW + (size_t)(mat - 1) * DD * DD);
  const int k0 = kk * 32 + (lane >> 4) * 8;
  const int col = nf * 16 + (lane & 15);
  ushort8v hv, lv;
#pragma unroll
  for (int j = 0; j < 8; ++j) {
    const float f = W[(size_t)(k0 + j) * DD + col];
    __hip_bfloat16 bh = __float2bfloat16(f);
    __hip_bfloat16 bl = __float2bfloat16(f - __bfloat162float(bh));
    hv[j] = *(ushort*)&bh;
    lv[j] = *(ushort*)&bl;
  }
  ushort* base = Wp + (size_t)mat * 32768;
  *(ushort8v*)(base + ((size_t)((kk * 8 + nf) * 2 + 0) * 64 + lane) * 8) = hv;
  *(ushort8v*)(base + ((size_t)((kk * 8 + nf) * 2 + 1) * 64 + lane) * 8) = lv;
}

// ============ fused [gather-sum +] GEMM + ReLU [+ LN] ============
// Block 256 = 4 waves, tile 64 rows x 128 cols. Wave w owns rows w*16..+15.
// Each HALF-WAVE (32 lanes, lane covers 4 cols) streams 8 rows, software-
// pipelined one row ahead (self-row + csr indices prefetched). Register
// accumulation only — no atomics, no barriers (wave-private LDS slices).
template<int MODE>
__global__ __launch_bounds__(256, 4)
void gemm_node(const float* __restrict__ Xf, const ushort* __restrict__ Hin,
               const int* __restrict__ csr, const int* __restrict__ offE,
               const ushort* __restrict__ Wp, const float* __restrict__ bias,
               const float* __restrict__ lng, const float* __restrict__ lnb,
               ushort* __restrict__ Hout) {
  __align__(16) __shared__ ushort AH[64 * 128];
  __align__(16) __shared__ ushort AL[64 * 128];
  const int t = threadIdx.x, lane = t & 63, w = t >> 6;
  const int hh = lane >> 5, l = lane & 31;
  const int r0 = blockIdx.x * 64;
  const int gbase = r0 + w * 16 + hh * 8;     // first global row of this half-wave
  const uint2* hu2 = (const uint2*)Hin;

  // ---- offset preload: lanes l<9 hold offE[gbase-1 .. gbase+7] ----
  int offv = 0;
  if (MODE == 1 && l < 9) {
    int gi = gbase - 1 + l;
    const int gic = gi < 0 ? 0 : (gi > NN - 1 ? NN - 1 : gi);
    offv = (gi < 0) ? 0 : offE[gic];
  }

  // self-row loader (cols 4l..4l+3)
  auto ldself = [&](int v) -> float4 {
    float4 r = {0.f, 0.f, 0.f, 0.f};
    if (v < NN) {
      if constexpr (MODE == 0) {
        r = *(const float4*)(Xf + (size_t)v * DD + 4 * l);
      } else {
        const uint2 g = hu2[(size_t)v * 32 + l];
        const float2 a = unpk2(g.x), b = unpk2(g.y);
        r.x = a.x; r.y = a.y; r.z = b.x; r.w = b.y;
      }
    }
    return r;
  };

  // ---- prologue: prefetch row 0 ----
  int v = gbase;
  float4 selfv = ldself(v);
  int i0 = 0, i1 = 0;
  int idx[8];
  if constexpr (MODE == 1) {
    i0 = __shfl(offv, hh * 32 + 0);
    i1 = __shfl(offv, hh * 32 + 1);
#pragma unroll
    for (int j = 0; j < 8; ++j) {
      int ij = i0 + j; ij = ij < NE ? ij : NE - 1;
      idx[j] = csr[ij];
    }
  }

#pragma unroll 1
  for (int s = 0; s < 8; ++s) {
    // 1) issue this row's gathers (indices already resident)
    uint2 g[8];
    if constexpr (MODE == 1) {
#pragma unroll
      for (int j = 0; j < 8; ++j) g[j] = hu2[(size_t)idx[j] * 32 + l];
    }
    // 2) prefetch next row (self + offsets + indices) — overlaps gather latency
    float4 selfn = {0.f, 0.f, 0.f, 0.f};
    int i0n = 0, i1n = 0, idxn[8];
    if (s < 7) {
      selfn = ldself(v + 1);
      if constexpr (MODE == 1) {
        i0n = __shfl(offv, hh * 32 + s + 1);
        i1n = __shfl(offv, hh * 32 + s + 2);
#pragma unroll
        for (int j = 0; j < 8; ++j) {
          int ij = i0n + j; ij = ij < NE ? ij : NE - 1;
          idxn[j] = csr[ij];
        }
      }
    }
    // 3) accumulate
    float4 ax = selfv;
    if constexpr (MODE == 1) {
#pragma unroll
      for (int j = 0; j < 8; ++j) {
        const bool ok = (i0 + j) < i1;
        const float2 fa = unpk2(g[j].x), fb = unpk2(g[j].y);
        ax.x += ok ? fa.x : 0.f;
        ax.y += ok ? fa.y : 0.f;
        ax.z += ok ? fb.x : 0.f;
        ax.w += ok ? fb.y : 0.f;
      }
      // rare tail: rows with deg > 8
      int i = i0 + 8;
#pragma unroll 1
      while (i < i1) {
#pragma unroll
        for (int j = 0; j < 8; ++j) {
          int ij = i + j; ij = ij < NE ? ij : NE - 1;
          const uint2 gg = hu2[(size_t)csr[ij] * 32 + l];
          const bool ok = (i + j) < i1;
          const float2 fa = unpk2(gg.x), fb = unpk2(gg.y);
          ax.x += ok ? fa.x : 0.f;
          ax.y += ok ? fa.y : 0.f;
          ax.z += ok ? fb.x : 0.f;
          ax.w += ok ? fb.y : 0.f;
        }
        i += 8;
      }
    }
    // 4) split hi/lo bf16 and store to wave-private LDS slice (swizzled)
    {
      uint h0, l0, h1, l1;
      split2(ax.x, ax.y, h0, l0);
      split2(ax.z, ax.w, h1, l1);
      const int row = v - r0;
      const int ch = l >> 1;
      const int uoff = (row * 16 + (ch ^ (row & 7))) * 8 + (l & 1) * 4;
      uint2 hv2; hv2.x = h0; hv2.y = h1;
      uint2 lv2; lv2.x = l0; lv2.y = l1;
      *(uint2*)&AH[uoff] = hv2;
      *(uint2*)&AL[uoff] = lv2;
    }
    // 5) rotate pipeline
    selfv = selfn; i0 = i0n; i1 = i1n;
    if constexpr (MODE == 1) {
#pragma unroll
      for (int j = 0; j < 8; ++j) idx[j] = idxn[j];
    }
    ++v;
  }
  // no barrier: each wave reads only its own staged rows below

  // ---- MFMA phase ----
  f32x4 accv[8];
#pragma unroll
  for (int nf = 0; nf < 8; ++nf) accv[nf] = (f32x4){0.f, 0.f, 0.f, 0.f};
  const int arow = w * 16 + (lane & 15);
  const int q = lane >> 4;
  const int rx = arow & 7;
#pragma unroll
  for (int kk = 0; kk < 4; ++kk) {
    const int aidx = (arow * 16 + ((kk * 4 + q) ^ rx)) * 8;
    const short8v ah = *(const short8v*)&AH[aidx];
    const short8v al = *(const short8v*)&AL[aidx];
#pragma unroll
    for (int nf = 0; nf < 8; ++nf) {
      const ushort* bp = Wp + ((size_t)((kk * 8 + nf) * 2) * 64 + lane) * 8;
      const short8v bh = *(const short8v*)bp;
      const short8v bl = *(const short8v*)(bp + 64 * 8);
      accv[nf] = __builtin_amdgcn_mfma_f32_16x16x32_bf16(ah, bh, accv[nf], 0, 0, 0);
      accv[nf] = __builtin_amdgcn_mfma_f32_16x16x32_bf16(al, bh, accv[nf], 0, 0, 0);
      accv[nf] = __builtin_amdgcn_mfma_f32_16x16x32_bf16(ah, bl, accv[nf], 0, 0, 0);
    }
  }

  // ---- epilogue: bias + ReLU [+ LN], store bf16 ----
  const int colb = lane & 15;
  float bias8[8], g8[8], q8[8];
#pragma unroll
  for (int nf = 0; nf < 8; ++nf) {
    bias8[nf] = bias[nf * 16 + colb];
    if (MODE == 1) { g8[nf] = lng[nf * 16 + colb]; q8[nf] = lnb[nf * 16 + colb]; }
  }
#pragma unroll
  for (int r = 0; r < 4; ++r) {
    const int grow = r0 + w * 16 + (lane >> 4) * 4 + r;
    float z[8];
    float s = 0.f, s2 = 0.f;
#pragma unroll
    for (int nf = 0; nf < 8; ++nf) {
      z[nf] = fmaxf(accv[nf][r] + bias8[nf], 0.f);
      s += z[nf];
      s2 += z[nf] * z[nf];
    }
    if (MODE == 1) {
#pragma unroll
      for (int o = 1; o < 16; o <<= 1) { s += __shfl_xor(s, o); s2 += __shfl_xor(s2, o); }
      const float mu = s * (1.f / DD);
      const float inv = rsqrtf(s2 * (1.f / DD) - mu * mu + LN_EPS);
#pragma unroll
      for (int nf = 0; nf < 8; ++nf) z[nf] = (z[nf] - mu) * inv * g8[nf] + q8[nf];
    }
    if (grow < NN) {
      ushort* yp = Hout + (size_t)grow * DD + colb;
#pragma unroll
      for (int nf = 0; nf < 8; ++nf) {
        __hip_bfloat16 b = __float2bfloat16(z[nf]);
        yp[nf * 16] = *(ushort*)&b;
      }
    }
  }
}

// ============ pool (bf16 h, batch_ids sorted) ============
__global__ __launch_bounds__(128)
void pool_kernel(const ushort* __restrict__ h, const int* __restrict__ batch,
                 float* __restrict__ sums, float* __restrict__ counts) {
  const int c = threadIdx.x;
  const int base = blockIdx.x * 64;
  const int end = (base + 64 < NN) ? base + 64 : NN;
  int cur = batch[base];
  float acc = 0.f, cnt = 0.f;
  for (int r = base; r < end; ++r) {
    const int g = batch[r];
    if (g != cur) {
      __hip_atomic_fetch_add(&sums[cur * DD + c], acc, __ATOMIC_RELAXED, __HIP_MEMORY_SCOPE_AGENT);
      if (c == 0)
        __hip_atomic_fetch_add(&counts[cur], cnt, __ATOMIC_RELAXED, __HIP_MEMORY_SCOPE_AGENT);
      acc = 0.f; cnt = 0.f; cur = g;
    }
    acc += __uint_as_float(((uint)h[(size_t)r * DD + c]) << 16);
    cnt += 1.f;
  }
  __hip_atomic_fetch_add(&sums[cur * DD + c], acc, __ATOMIC_RELAXED, __HIP_MEMORY_SCOPE_AGENT);
  if (c == 0)
    __hip_atomic_fetch_add(&counts[cur], cnt, __ATOMIC_RELAXED, __HIP_MEMORY_SCOPE_AGENT);
}

__global__ __launch_bounds__(256)
void finalize_kernel(const float* __restrict__ sums, const float* __restrict__ counts,
                     float* __restrict__ out) {
  const int i = blockIdx.x * 256 + threadIdx.x;
  if (i >= NG * DD) return;
  out[i] = sums[i] / fmaxf(counts[i >> 7], 1.f);
}

extern "C" void kernel_launch(void* const* d_in, const int* in_sizes, int n_in,
                              void* d_out, int out_size, void* d_ws, size_t ws_size,
                              hipStream_t stream) {
  const float* x     = (const float*)d_in[0];
  const int*   ei    = (const int*)d_in[1];
  const int*   batch = (const int*)d_in[2];
  const float* projW = (const float*)d_in[3];
  const float* projb = (const float*)d_in[4];
  const float* mlpW  = (const float*)d_in[5];
  const float* mlpb  = (const float*)d_in[6];
  const float* lng   = (const float*)d_in[7];
  const float* lnb   = (const float*)d_in[8];
  float* out = (float*)d_out;

  char* ws = (char*)d_ws;
  ushort* hA    = (ushort*)(ws + 0);           // 25,600,000 B
  ushort* hB    = (ushort*)(ws + 25600000);    // 25,600,000 B
  int*   csr    = (int*)   (ws + 51200000);    //  2,400,000 B
  int*   deg    = (int*)   (ws + 53600000);    //    400,000 B
  int*   off    = (int*)   (ws + 54000000);    //    400,000 B
  int*   btot   = (int*)   (ws + 54400000);    //        512 B
  ushort* Wp    = (ushort*)(ws + 54400512);    //    262,144 B
  float* sums   = (float*) (ws + 54662656);    //     32,768 B
  float* counts = (float*) (ws + 54695424);    //        256 B

  const int* src = ei;
  const int* dst = ei + NE;

  // ---- CSR build ----
  hipMemsetAsync(deg, 0, NN * sizeof(int), stream);
  count_kernel<<<(NE + 255) / 256, 256, 0, stream>>>(dst, deg);
  scan_a<<<(NN + 1023) / 1024, 256, 0, stream>>>(deg, off, btot);
  scan_b<<<1, 128, 0, stream>>>(btot, (NN + 1023) / 1024);
  scan_c<<<(NN + 255) / 256, 256, 0, stream>>>(off, btot);
  fill_kernel<<<(NE + 255) / 256, 256, 0, stream>>>(src, dst, off, csr);

  // ---- weight prep ----
  wprep_kernel<<<32, 256, 0, stream>>>(projW, mlpW, Wp);

  const int gemm_blocks = (NN + 63) / 64;   // 1563

  // h = relu(x @ projW + projb) -> bf16
  gemm_node<0><<<gemm_blocks, 256, 0, stream>>>(
      x, nullptr, nullptr, nullptr, Wp, projb, nullptr, nullptr, hA);

  // 3 fused GIN layers, ping-pong hA/hB
  ushort* hin = hA;
  ushort* hout = hB;
  for (int l = 0; l < NL; ++l) {
    gemm_node<1><<<gemm_blocks, 256, 0, stream>>>(
        nullptr, hin, csr, off, Wp + (size_t)(1 + l) * 32768,
        mlpb + (size_t)l * DD, lng + (size_t)l * DD, lnb + (size_t)l * DD, hout);
    ushort* tmp = hin; hin = hout; hout = tmp;
  }

  hipMemsetAsync(sums, 0, (size_t)(NG * DD + NG) * sizeof(float), stream);
  pool_kernel<<<(NN + 63) / 64, 128, 0, stream>>>(hin, batch, sums, counts);
  finalize_kernel<<<(NG * DD + 255) / 256, 256, 0, stream>>>(sums, counts, out);
}

// Round 6
// 268.671 us; speedup vs baseline: 5.5186x; 1.0647x over previous
//
#include <hip/hip_runtime.h>
#include <hip/hip_bf16.h>

#define NN 100000
#define NE 600000
#define DD 128
#define NL 3
#define NG 64
#define LN_EPS 1e-5f

typedef __attribute__((ext_vector_type(8))) short short8v;
typedef __attribute__((ext_vector_type(8))) unsigned short ushort8v;
typedef __attribute__((ext_vector_type(4))) float f32x4;
typedef unsigned short ushort;
typedef unsigned int uint;

// unpack dword of 2 bf16 (cols c, c+1) to fp32
__device__ inline float2 unpk2(uint u) {
  float2 r;
  r.x = __uint_as_float(u << 16);
  r.y = __uint_as_float(u & 0xffff0000u);
  return r;
}

// split fp32 pair -> (hi bf16 pair, lo bf16 pair); hi = truncate, lo = RNE(residual)
__device__ inline void split2(float ax, float ay, uint& hi2, uint& lo2) {
  const uint ux = __float_as_uint(ax), uy = __float_as_uint(ay);
  hi2 = (ux >> 16) | (uy & 0xffff0000u);
  const float rx = ax - __uint_as_float(ux & 0xffff0000u);
  const float ry = ay - __uint_as_float(uy & 0xffff0000u);
  __hip_bfloat16 bx = __float2bfloat16(rx), by = __float2bfloat16(ry);
  lo2 = (uint)*(ushort*)&bx | ((uint)*(ushort*)&by << 16);
}

// ============ CSR build ============
__global__ __launch_bounds__(256)
void count_kernel(const int* __restrict__ dst, int* __restrict__ deg) {
  const int e = blockIdx.x * 256 + threadIdx.x;
  if (e < NE) atomicAdd(&deg[dst[e]], 1);
}

__global__ __launch_bounds__(256)
void scan_a(const int* __restrict__ deg, int* __restrict__ off, int* __restrict__ btot) {
  __shared__ int wsum[4];
  const int t = threadIdx.x, lane = t & 63, wid = t >> 6;
  const int base = blockIdx.x * 1024 + t * 4;
  int4 d = {0, 0, 0, 0};
  if (base < NN) d = *(const int4*)(deg + base);
  const int s0 = d.x, s1 = s0 + d.y, s2 = s1 + d.z, s3 = s2 + d.w;
  int v = s3;
#pragma unroll
  for (int o = 1; o < 64; o <<= 1) { const int u = __shfl_up(v, o); if (lane >= o) v += u; }
  if (lane == 63) wsum[wid] = v;
  __syncthreads();
  if (t == 0) {
    int a = 0;
#pragma unroll
    for (int i = 0; i < 4; ++i) { const int x = wsum[i]; wsum[i] = a; a += x; }
    btot[blockIdx.x] = a;
  }
  __syncthreads();
  const int texcl = wsum[wid] + v - s3;
  if (base < NN) {
    const int4 o4 = {texcl, texcl + s0, texcl + s1, texcl + s2};
    *(int4*)(off + base) = o4;
  }
}

__global__ __launch_bounds__(128)
void scan_b(int* __restrict__ btot, int nb) {
  __shared__ int wsum[2];
  const int t = threadIdx.x, lane = t & 63, wid = t >> 6;
  const int x = (t < nb) ? btot[t] : 0;
  int v = x;
#pragma unroll
  for (int o = 1; o < 64; o <<= 1) { const int u = __shfl_up(v, o); if (lane >= o) v += u; }
  if (lane == 63) wsum[wid] = v;
  __syncthreads();
  if (t == 0) { const int w0 = wsum[0]; wsum[0] = 0; wsum[1] = w0; }
  __syncthreads();
  const int excl = wsum[wid] + v - x;
  if (t < nb) btot[t] = excl;
}

__global__ __launch_bounds__(256)
void scan_c(int* __restrict__ off, const int* __restrict__ btot) {
  const int i = blockIdx.x * 256 + threadIdx.x;
  if (i < NN) off[i] += btot[i >> 10];
}

// fill: atomicAdd turns off[] starts into ends; csr = src per dst bucket
__global__ __launch_bounds__(256)
void fill_kernel(const int* __restrict__ src, const int* __restrict__ dst,
                 int* __restrict__ off, int* __restrict__ csr) {
  const int e = blockIdx.x * 256 + threadIdx.x;
  if (e < NE) {
    const int p = atomicAdd(&off[dst[e]], 1);
    csr[p] = src[e];
  }
}

// ============ weight prep: fragment-ordered bf16 hi/lo ============
__global__ __launch_bounds__(256)
void wprep_kernel(const float* __restrict__ projW, const float* __restrict__ mlpW,
                  ushort* __restrict__ Wp) {
  const int tid = blockIdx.x * 256 + threadIdx.x;   // 8192 total
  const int lane = tid & 63;
  const int fid = tid >> 6;                         // 0..127
  const int mat = fid >> 5;
  const int rem = fid & 31;
  const int kk = rem >> 3, nf = rem & 7;
  const float* W = (mat == 0) ? projW : (mlpW + (size_t)(mat - 1) * DD * DD);
  const int k0 = kk * 32 + (lane >> 4) * 8;
  const int col = nf * 16 + (lane & 15);
  ushort8v hv, lv;
#pragma unroll
  for (int j = 0; j < 8; ++j) {
    const float f = W[(size_t)(k0 + j) * DD + col];
    __hip_bfloat16 bh = __float2bfloat16(f);
    __hip_bfloat16 bl = __float2bfloat16(f - __bfloat162float(bh));
    hv[j] = *(ushort*)&bh;
    lv[j] = *(ushort*)&bl;
  }
  ushort* base = Wp + (size_t)mat * 32768;
  *(ushort8v*)(base + ((size_t)((kk * 8 + nf) * 2 + 0) * 64 + lane) * 8) = hv;
  *(ushort8v*)(base + ((size_t)((kk * 8 + nf) * 2 + 1) * 64 + lane) * 8) = lv;
}

// ============ fused [gather-sum +] GEMM + ReLU [+ LN] ============
// Block 256 = 4 waves, tile 64 rows x 128 cols. Wave w owns rows w*16..+15.
// QUARTER-WAVE (16 lanes, lane = 1 chunk of 8 cols, uint4) streams 4 rows,
// depth-2 software pipeline; all neighbor indices preloaded to registers;
// invalid edges -> zero row NN (no per-edge predication). No atomics, no
// barriers (wave-private LDS slices). All hot addressing in 32-bit.
template<int MODE>
__global__ __launch_bounds__(256, 4)
void gemm_node(const float* __restrict__ Xf, const ushort* __restrict__ Hin,
               const int* __restrict__ csr, const int* __restrict__ offE,
               const ushort* __restrict__ Wp, const float* __restrict__ bias,
               const float* __restrict__ lng, const float* __restrict__ lnb,
               ushort* __restrict__ Hout) {
  __align__(16) __shared__ ushort AH[64 * 128];
  __align__(16) __shared__ ushort AL[64 * 128];
  const int t = threadIdx.x, lane = t & 63, w = t >> 6;
  const int q = lane >> 4;          // quarter 0..3
  const int ll = lane & 15;         // chunk index within row
  const int r0 = blockIdx.x * 64;
  const int qbase = r0 + w * 16 + q * 4;   // first global row of this quarter
  const uint4* __restrict__ hu4 = (const uint4*)Hin;

  if constexpr (MODE == 1) {
    // ---- offsets: lanes ll<5 hold offE[qbase-1 .. qbase+3] ----
    int offv = 0;
    if (ll < 5) {
      const int gi = qbase - 1 + ll;
      const int gic = gi < 0 ? 0 : (gi > NN - 1 ? NN - 1 : gi);
      offv = (gi < 0) ? 0 : offE[gic];
    }
    // ---- preload first-8 neighbor ids of all 4 rows (2 per lane) ----
    int idxA, idxB;   // idxA: rows 0-1 (lane ll -> row ll>>3, j=ll&7); idxB: rows 2-3
    {
      const int j = ll & 7;
      const int rA = ll >> 3;
      const int a0 = __shfl(offv, q * 16 + rA);
      const int a1 = __shfl(offv, q * 16 + rA + 1);
      int ii = a0 + j;
      int iic = ii < NE ? ii : NE - 1;
      const int cv = csr[iic];
      idxA = (ii < a1) ? cv : NN;
      const int rB = 2 + (ll >> 3);
      const int b0 = __shfl(offv, q * 16 + rB);
      const int b1 = __shfl(offv, q * 16 + rB + 1);
      ii = b0 + j;
      iic = ii < NE ? ii : NE - 1;
      const int cw = csr[iic];
      idxB = (ii < b1) ? cw : NN;
    }

    uint4 gA[9], gB[9];
    auto ISSUE = [&](int s, uint4 (&g)[9]) {   // s is compile-time at call sites
      const int bl = q * 16 + ((s & 1) << 3);
      const int srcv = (s < 2) ? idxA : idxB;
#pragma unroll
      for (int j = 0; j < 8; ++j) {
        const int id = __shfl(srcv, bl + j);
        g[j] = hu4[id * 16 + ll];
      }
      const int v = qbase + s;
      const int sid = (v < NN) ? v : NN;       // self (GIN eps=0); zero row if OOB
      g[8] = hu4[sid * 16 + ll];
    };
    auto CONSUME = [&](int s, uint4 (&g)[9]) {
      float4 ev = {0.f, 0.f, 0.f, 0.f}, od = {0.f, 0.f, 0.f, 0.f};
#pragma unroll
      for (int j = 0; j < 9; ++j) {
        const float2 a = unpk2(g[j].x), b = unpk2(g[j].y);
        const float2 c = unpk2(g[j].z), d = unpk2(g[j].w);
        ev.x += a.x; od.x += a.y; ev.y += b.x; od.y += b.y;
        ev.z += c.x; od.z += c.y; ev.w += d.x; od.w += d.y;
      }
      // rare tail: rows with deg > 8
      const int i0s = __shfl(offv, q * 16 + s);
      const int i1s = __shfl(offv, q * 16 + s + 1);
      int i = i0s + 8;
#pragma unroll 1
      while (i < i1s) {
#pragma unroll
        for (int jj = 0; jj < 4; ++jj) {
          const int ii = i + jj;
          const int iic = ii < NE ? ii : NE - 1;
          int id = csr[iic];
          id = (ii < i1s) ? id : NN;
          const uint4 gg = hu4[id * 16 + ll];
          const float2 a = unpk2(gg.x), b = unpk2(gg.y);
          const float2 c = unpk2(gg.z), d = unpk2(gg.w);
          ev.x += a.x; od.x += a.y; ev.y += b.x; od.y += b.y;
          ev.z += c.x; od.z += c.y; ev.w += d.x; od.w += d.y;
        }
        i += 4;
      }
      uint h0, l0, h1, l1, h2, l2, h3, l3;
      split2(ev.x, od.x, h0, l0);
      split2(ev.y, od.y, h1, l1);
      split2(ev.z, od.z, h2, l2);
      split2(ev.w, od.w, h3, l3);
      const int row = w * 16 + q * 4 + s;
      const int uoff = (row * 16 + (ll ^ (row & 7))) * 8;
      *(uint4*)&AH[uoff] = make_uint4(h0, h1, h2, h3);
      *(uint4*)&AL[uoff] = make_uint4(l0, l1, l2, l3);
    };

    ISSUE(0, gA);
    ISSUE(1, gB);
    CONSUME(0, gA);
    ISSUE(2, gA);
    CONSUME(1, gB);
    ISSUE(3, gB);
    CONSUME(2, gA);
    CONSUME(3, gB);
  } else {
    // ---- MODE 0: self-row only (fp32 X), depth-2 pipeline ----
    const float4* __restrict__ Xf4 = (const float4*)Xf;
    float4 a0, b0, a1, b1;
    auto LOADX = [&](int s, float4& fa, float4& fb) {
      int v = qbase + s;
      v = v < NN ? v : NN - 1;        // clamp; masked rows never stored
      fa = Xf4[v * 32 + 2 * ll];
      fb = Xf4[v * 32 + 2 * ll + 1];
    };
    auto STOREX = [&](int s, const float4& fa, const float4& fb) {
      uint h0, l0, h1, l1, h2, l2, h3, l3;
      split2(fa.x, fa.y, h0, l0);
      split2(fa.z, fa.w, h1, l1);
      split2(fb.x, fb.y, h2, l2);
      split2(fb.z, fb.w, h3, l3);
      const int row = w * 16 + q * 4 + s;
      const int uoff = (row * 16 + (ll ^ (row & 7))) * 8;
      *(uint4*)&AH[uoff] = make_uint4(h0, h1, h2, h3);
      *(uint4*)&AL[uoff] = make_uint4(l0, l1, l2, l3);
    };
    LOADX(0, a0, b0);
    LOADX(1, a1, b1);
    STOREX(0, a0, b0);
    LOADX(2, a0, b0);
    STOREX(1, a1, b1);
    LOADX(3, a1, b1);
    STOREX(2, a0, b0);
    STOREX(3, a1, b1);
  }
  // no barrier: each wave reads only its own staged rows below

  // ---- MFMA phase ----
  f32x4 accv[8];
#pragma unroll
  for (int nf = 0; nf < 8; ++nf) accv[nf] = (f32x4){0.f, 0.f, 0.f, 0.f};
  const int arow = w * 16 + (lane & 15);
  const int qq = lane >> 4;
  const int rx = arow & 7;
#pragma unroll
  for (int kk = 0; kk < 4; ++kk) {
    const int aidx = (arow * 16 + ((kk * 4 + qq) ^ rx)) * 8;
    const short8v ah = *(const short8v*)&AH[aidx];
    const short8v al = *(const short8v*)&AL[aidx];
#pragma unroll
    for (int nf = 0; nf < 8; ++nf) {
      const ushort* bp = Wp + ((size_t)((kk * 8 + nf) * 2) * 64 + lane) * 8;
      const short8v bh = *(const short8v*)bp;
      const short8v bl = *(const short8v*)(bp + 64 * 8);
      accv[nf] = __builtin_amdgcn_mfma_f32_16x16x32_bf16(ah, bh, accv[nf], 0, 0, 0);
      accv[nf] = __builtin_amdgcn_mfma_f32_16x16x32_bf16(al, bh, accv[nf], 0, 0, 0);
      accv[nf] = __builtin_amdgcn_mfma_f32_16x16x32_bf16(ah, bl, accv[nf], 0, 0, 0);
    }
  }

  // ---- epilogue: bias + ReLU [+ LN], store bf16 ----
  const int colb = lane & 15;
  float bias8[8], g8[8], q8[8];
#pragma unroll
  for (int nf = 0; nf < 8; ++nf) {
    bias8[nf] = bias[nf * 16 + colb];
    if (MODE == 1) { g8[nf] = lng[nf * 16 + colb]; q8[nf] = lnb[nf * 16 + colb]; }
  }
#pragma unroll
  for (int r = 0; r < 4; ++r) {
    const int grow = r0 + w * 16 + (lane >> 4) * 4 + r;
    float z[8];
    float s = 0.f, s2 = 0.f;
#pragma unroll
    for (int nf = 0; nf < 8; ++nf) {
      z[nf] = fmaxf(accv[nf][r] + bias8[nf], 0.f);
      s += z[nf];
      s2 += z[nf] * z[nf];
    }
    if (MODE == 1) {
#pragma unroll
      for (int o = 1; o < 16; o <<= 1) { s += __shfl_xor(s, o); s2 += __shfl_xor(s2, o); }
      const float mu = s * (1.f / DD);
      const float inv = rsqrtf(s2 * (1.f / DD) - mu * mu + LN_EPS);
#pragma unroll
      for (int nf = 0; nf < 8; ++nf) z[nf] = (z[nf] - mu) * inv * g8[nf] + q8[nf];
    }
    if (grow < NN) {
      ushort* yp = Hout + grow * DD + colb;
#pragma unroll
      for (int nf = 0; nf < 8; ++nf) {
        __hip_bfloat16 b = __float2bfloat16(z[nf]);
        yp[nf * 16] = *(ushort*)&b;
      }
    }
  }
}

// ============ pool (bf16 h, batch_ids sorted; 64 threads, uint loads) ============
__global__ __launch_bounds__(64)
void pool_kernel(const ushort* __restrict__ h, const int* __restrict__ batch,
                 float* __restrict__ sums, float* __restrict__ counts) {
  const int c = threadIdx.x;                 // uint index: cols 2c, 2c+1
  const int base = blockIdx.x * 64;
  const int end = (base + 64 < NN) ? base + 64 : NN;
  const uint* __restrict__ hu = (const uint*)h;
  int cur = batch[base];
  float a0 = 0.f, a1 = 0.f, cnt = 0.f;
  for (int r = base; r < end; ++r) {
    const int g = batch[r];
    if (g != cur) {
      __hip_atomic_fetch_add(&sums[cur * DD + 2 * c], a0, __ATOMIC_RELAXED, __HIP_MEMORY_SCOPE_AGENT);
      __hip_atomic_fetch_add(&sums[cur * DD + 2 * c + 1], a1, __ATOMIC_RELAXED, __HIP_MEMORY_SCOPE_AGENT);
      if (c == 0)
        __hip_atomic_fetch_add(&counts[cur], cnt, __ATOMIC_RELAXED, __HIP_MEMORY_SCOPE_AGENT);
      a0 = 0.f; a1 = 0.f; cnt = 0.f; cur = g;
    }
    const float2 f = unpk2(hu[r * 64 + c]);
    a0 += f.x; a1 += f.y; cnt += 1.f;
  }
  __hip_atomic_fetch_add(&sums[cur * DD + 2 * c], a0, __ATOMIC_RELAXED, __HIP_MEMORY_SCOPE_AGENT);
  __hip_atomic_fetch_add(&sums[cur * DD + 2 * c + 1], a1, __ATOMIC_RELAXED, __HIP_MEMORY_SCOPE_AGENT);
  if (c == 0)
    __hip_atomic_fetch_add(&counts[cur], cnt, __ATOMIC_RELAXED, __HIP_MEMORY_SCOPE_AGENT);
}

__global__ __launch_bounds__(256)
void finalize_kernel(const float* __restrict__ sums, const float* __restrict__ counts,
                     float* __restrict__ out) {
  const int i = blockIdx.x * 256 + threadIdx.x;
  if (i >= NG * DD) return;
  out[i] = sums[i] / fmaxf(counts[i >> 7], 1.f);
}

extern "C" void kernel_launch(void* const* d_in, const int* in_sizes, int n_in,
                              void* d_out, int out_size, void* d_ws, size_t ws_size,
                              hipStream_t stream) {
  const float* x     = (const float*)d_in[0];
  const int*   ei    = (const int*)d_in[1];
  const int*   batch = (const int*)d_in[2];
  const float* projW = (const float*)d_in[3];
  const float* projb = (const float*)d_in[4];
  const float* mlpW  = (const float*)d_in[5];
  const float* mlpb  = (const float*)d_in[6];
  const float* lng   = (const float*)d_in[7];
  const float* lnb   = (const float*)d_in[8];
  float* out = (float*)d_out;

  char* ws = (char*)d_ws;
  ushort* hA    = (ushort*)(ws + 0);           // (NN+1)*256 B = 25,600,256
  ushort* hB    = (ushort*)(ws + 25600256);    // 25,600,256 B
  int*   csr    = (int*)   (ws + 51200512);    //  2,400,000 B
  int*   deg    = (int*)   (ws + 53600512);    //    400,000 B
  int*   off    = (int*)   (ws + 54000512);    //    400,000 B
  int*   btot   = (int*)   (ws + 54400512);    //        512 B
  ushort* Wp    = (ushort*)(ws + 54401024);    //    262,144 B
  float* sums   = (float*) (ws + 54663168);    //     32,768 B
  float* counts = (float*) (ws + 54695936);    //        256 B

  const int* src = ei;
  const int* dst = ei + NE;

  // zero rows (index NN) for the gather zero-target
  hipMemsetAsync(hA + (size_t)NN * DD, 0, DD * sizeof(ushort), stream);
  hipMemsetAsync(hB + (size_t)NN * DD, 0, DD * sizeof(ushort), stream);

  // ---- CSR build ----
  hipMemsetAsync(deg, 0, NN * sizeof(int), stream);
  count_kernel<<<(NE + 255) / 256, 256, 0, stream>>>(dst, deg);
  scan_a<<<(NN + 1023) / 1024, 256, 0, stream>>>(deg, off, btot);
  scan_b<<<1, 128, 0, stream>>>(btot, (NN + 1023) / 1024);
  scan_c<<<(NN + 255) / 256, 256, 0, stream>>>(off, btot);
  fill_kernel<<<(NE + 255) / 256, 256, 0, stream>>>(src, dst, off, csr);

  // ---- weight prep ----
  wprep_kernel<<<32, 256, 0, stream>>>(projW, mlpW, Wp);

  const int gemm_blocks = (NN + 63) / 64;   // 1563

  // h = relu(x @ projW + projb) -> bf16
  gemm_node<0><<<gemm_blocks, 256, 0, stream>>>(
      x, nullptr, nullptr, nullptr, Wp, projb, nullptr, nullptr, hA);

  // 3 fused GIN layers, ping-pong hA/hB
  ushort* hin = hA;
  ushort* hout = hB;
  for (int l = 0; l < NL; ++l) {
    gemm_node<1><<<gemm_blocks, 256, 0, stream>>>(
        nullptr, hin, csr, off, Wp + (size_t)(1 + l) * 32768,
        mlpb + (size_t)l * DD, lng + (size_t)l * DD, lnb + (size_t)l * DD, hout);
    ushort* tmp = hin; hin = hout; hout = tmp;
  }

  hipMemsetAsync(sums, 0, (size_t)(NG * DD + NG) * sizeof(float), stream);
  pool_kernel<<<(NN + 63) / 64, 64, 0, stream>>>(hin, batch, sums, counts);
  finalize_kernel<<<(NG * DD + 255) / 256, 256, 0, stream>>>(sums, counts, out);
}